// Round 8
// baseline (252.452 us; speedup 1.0000x reference)
//
#include <hip/hip_runtime.h>
#include <hip/hip_bf16.h>

// GATConv on gfx950.
// prep (W->bf16 + cursor init) | MFMA GEMM (fp32 feat cvt in reg, h bf16,
// el/er fused epilogue) | scatter: coarse bins (dst>>8), per-block LDS hist ->
// one global atomic per (block,bin) reserves a contiguous run (512 blocks ->
// ~16-edge = 64B full-line runs) | build_csr: 1568 blocks, one per 32-dst
// slice; each reads its bucket's arena, 32-bin LDS hist+scan, then computes
// w=exp(lrelu(el[u]+er[d])) (no max-sub: |e|<~25 << 88) and writes packed
// (bf16(w)<<16|src) densely into a PRIVATE slice region (row_beg/row_end
// explicit, regions need not be globally dense) | gat: one wave per dst;
// single shfl-broadcast per edge (w precomputed), coalesced bf16 h gathers.

#define IN_FEATS 256
#define OUT_FEATS 128
#define NBINS 256              // coarse buckets (dst>>8); 196 used at N=50000
#define CAPB_LOG 14
#define CAPB (1 << CAPB_LOG)   // per-bucket arena capacity (mean 8192, +90sig)
#define SCAT_BLOCKS 512
#define SLICE_DSTS 32          // dsts per build_csr block
#define SCAP 2048              // per-slice edge capacity (mean 1024, +32sig)

typedef __bf16 bf16x8 __attribute__((ext_vector_type(8)));
typedef float f32x4 __attribute__((ext_vector_type(4)));

__global__ void prep(const float* __restrict__ W, __bf16* __restrict__ Wb, int nw,
                     int* __restrict__ cur) {
    int i = blockIdx.x * 256 + threadIdx.x;
    if (i < nw) Wb[i] = (__bf16)W[i];
    if (i < NBINS) cur[i] = i << CAPB_LOG;
}

// ---------------- MFMA GEMM: h[m][n] = sum_k feat[m][k] * W[n][k] ----------
__global__ __launch_bounds__(256) void gemm_mfma(const float* __restrict__ feat,
                                                 const __bf16* __restrict__ Wb,
                                                 const float* __restrict__ attn_l,
                                                 const float* __restrict__ attn_r,
                                                 __bf16* __restrict__ hb,
                                                 float* __restrict__ el,
                                                 float* __restrict__ er, int n) {
    const int wid = threadIdx.x >> 6;
    const int lane = threadIdx.x & 63;
    const int s = lane & 15;
    const int q = lane >> 4;
    const int m0 = blockIdx.x * 64 + wid * 16;
    if (m0 >= n) return;

    const int mrow = min(m0 + s, n - 1);
    const float* arow = feat + (size_t)mrow * IN_FEATS + q * 8;

    f32x4 acc[8];
#pragma unroll
    for (int nt = 0; nt < 8; nt++) acc[nt] = (f32x4){0.f, 0.f, 0.f, 0.f};

#pragma unroll
    for (int ks = 0; ks < 8; ks++) {
        const int k0 = ks * 32;
        float4 f0 = *(const float4*)(arow + k0);
        float4 f1 = *(const float4*)(arow + k0 + 4);
        bf16x8 a;
        a[0] = (__bf16)f0.x; a[1] = (__bf16)f0.y; a[2] = (__bf16)f0.z; a[3] = (__bf16)f0.w;
        a[4] = (__bf16)f1.x; a[5] = (__bf16)f1.y; a[6] = (__bf16)f1.z; a[7] = (__bf16)f1.w;
#pragma unroll
        for (int nt = 0; nt < 8; nt++) {
            bf16x8 b = *(const bf16x8*)(Wb + (size_t)(nt * 16 + s) * IN_FEATS + k0 + q * 8);
            acc[nt] = __builtin_amdgcn_mfma_f32_16x16x32_bf16(a, b, acc[nt], 0, 0, 0);
        }
    }

    float al[8], ar[8];
#pragma unroll
    for (int nt = 0; nt < 8; nt++) {
        al[nt] = attn_l[nt * 16 + s];
        ar[nt] = attn_r[nt * 16 + s];
    }

#pragma unroll
    for (int r = 0; r < 4; r++) {
        const int row = m0 + q * 4 + r;
        const bool ok = row < n;
        float pl = 0.f, pr = 0.f;
#pragma unroll
        for (int nt = 0; nt < 8; nt++) {
            float v = acc[nt][r];
            if (ok) hb[(size_t)row * OUT_FEATS + nt * 16 + s] = (__bf16)v;
            pl += v * al[nt];
            pr += v * ar[nt];
        }
#pragma unroll
        for (int m = 1; m < 16; m <<= 1) {
            pl += __shfl_xor(pl, m);
            pr += __shfl_xor(pr, m);
        }
        if (ok && s == 0) {
            el[row] = pl;
            er[row] = pr;
        }
    }
}

// ------- scatter: LDS hist -> per-(block,bin) global reservation -> place ----
__global__ __launch_bounds__(256) void scatter_kernel(const int* __restrict__ src,
                                                      const int* __restrict__ dst,
                                                      int* __restrict__ bin_cur,
                                                      unsigned* __restrict__ arena,
                                                      int E) {
    __shared__ int h[NBINS];
    __shared__ int base[NBINS];
    const int t = threadIdx.x;
    h[t] = 0;
    __syncthreads();
    const int chunk = (E + gridDim.x - 1) / gridDim.x;
    const int beg = blockIdx.x * chunk;
    const int end = min(beg + chunk, E);
    for (int i = beg + t; i < end; i += 256)
        atomicAdd(&h[dst[i] >> 8], 1);                 // LDS atomic
    __syncthreads();
    if (h[t] > 0)
        base[t] = atomicAdd(&bin_cur[t], h[t]);        // one global atomic/bin
    h[t] = 0;
    __syncthreads();
    for (int i = beg + t; i < end; i += 256) {
        int d = dst[i];
        int bin = d >> 8;
        int pos = base[bin] + atomicAdd(&h[bin], 1);   // LDS rank
        pos = min(pos, ((bin + 1) << CAPB_LOG) - 1);   // overflow clamp (P~0)
        arena[pos] = ((unsigned)d << 16) | (unsigned)src[i];
    }
}

// ---- build_csr: one block per 32-dst slice; private dense slice region ----
__global__ __launch_bounds__(256) void build_csr(const unsigned* __restrict__ arena,
                                                 const int* __restrict__ bin_cur,
                                                 const float* __restrict__ el,
                                                 const float* __restrict__ er,
                                                 unsigned* __restrict__ edges,
                                                 int* __restrict__ row_beg,
                                                 int* __restrict__ row_end,
                                                 int N, int edges_cap) {
    __shared__ int cnt[SLICE_DSTS];
    __shared__ int off[SLICE_DSTS];
    const int blk = blockIdx.x;            // = bucket*8 + slice
    const int b = blk >> 3;
    const int j = blk & 7;
    const int t = threadIdx.x;
    const int abeg = b << CAPB_LOG;
    const int aend = min(bin_cur[b], abeg + CAPB);

    if (t < SLICE_DSTS) cnt[t] = 0;
    __syncthreads();
    for (int i = abeg + t; i < aend; i += 256) {
        int d8 = (arena[i] >> 16) & 255;
        if ((d8 >> 5) == j) atomicAdd(&cnt[d8 & 31], 1);
    }
    __syncthreads();
    if (t < SLICE_DSTS) off[t] = cnt[t];
    __syncthreads();
    for (int o = 1; o < SLICE_DSTS; o <<= 1) {         // inclusive scan
        int v = (t >= o && t < SLICE_DSTS) ? off[t - o] : 0;
        __syncthreads();
        if (t < SLICE_DSTS) off[t] += v;
        __syncthreads();
    }
    int mycnt = 0, excl = 0;
    if (t < SLICE_DSTS) {
        mycnt = cnt[t];
        excl = off[t] - mycnt;
    }
    __syncthreads();
    if (t < SLICE_DSTS) off[t] = excl;                 // exclusive offsets
    __syncthreads();

    const int sbase = blk * SCAP;
    if (t < SLICE_DSTS) {
        int v = (b << 8) + j * SLICE_DSTS + t;
        if (v < N) {
            row_beg[v] = sbase + excl;
            row_end[v] = sbase + excl + mycnt;
        }
        cnt[t] = 0;
    }
    __syncthreads();
    for (int i = abeg + t; i < aend; i += 256) {
        unsigned e = arena[i];
        int d8 = (e >> 16) & 255;
        if ((d8 >> 5) != j) continue;
        int u = (int)(e & 0xFFFFu);
        int d = (b << 8) + d8;
        float x = el[u] + er[d];
        x = (x > 0.f) ? x : 0.2f * x;
        float w = __expf(x);
        int r = atomicAdd(&cnt[d8 & 31], 1);           // LDS rank
        int pos = sbase + off[d8 & 31] + r;
        pos = min(pos, edges_cap - 1);                 // safety clamp (P~0)
        edges[pos] = (__float_as_uint(w) & 0xFFFF0000u) | (unsigned)u;
    }
}

// ---------------- aggregation: one wave per dst node ----------------
__global__ __launch_bounds__(256) void gat_kernel(const __bf16* __restrict__ hb,
                                                  const unsigned* __restrict__ edges,
                                                  const int* __restrict__ row_beg,
                                                  const int* __restrict__ row_end,
                                                  float* __restrict__ out, int n) {
    const int v = blockIdx.x * 4 + (threadIdx.x >> 6);
    if (v >= n) return;
    const int lane = threadIdx.x & 63;
    const int beg = row_beg[v];
    const int end = row_end[v];
    const unsigned* hbu = (const unsigned*)hb;

    float acc0 = 0.f, acc1 = 0.f, wsum = 0.f;
    for (int c0 = beg; c0 < end; c0 += 64) {
        const int nn = min(64, end - c0);
        int my = (c0 + lane < end) ? (int)edges[c0 + lane] : 0;

        int k = 0;
        for (; k + 4 <= nn; k += 4) {
#pragma unroll
            for (int tt = 0; tt < 4; tt++) {
                unsigned e = (unsigned)__shfl(my, k + tt);
                int u = (int)(e & 0xFFFFu);
                float w = __uint_as_float(e & 0xFFFF0000u);
                wsum += w;
                unsigned pair = hbu[(size_t)u * (OUT_FEATS / 2) + lane];
                acc0 += w * __uint_as_float(pair << 16);
                acc1 += w * __uint_as_float(pair & 0xffff0000u);
            }
        }
        for (; k < nn; k++) {
            unsigned e = (unsigned)__shfl(my, k);
            int u = (int)(e & 0xFFFFu);
            float w = __uint_as_float(e & 0xFFFF0000u);
            wsum += w;
            unsigned pair = hbu[(size_t)u * (OUT_FEATS / 2) + lane];
            acc0 += w * __uint_as_float(pair << 16);
            acc1 += w * __uint_as_float(pair & 0xffff0000u);
        }
    }
    const float dnm = fmaxf(wsum, 1e-9f);
    float2 o = make_float2(acc0 / dnm, acc1 / dnm);
    *(float2*)(out + (size_t)v * OUT_FEATS + lane * 2) = o;
}

extern "C" void kernel_launch(void* const* d_in, const int* in_sizes, int n_in,
                              void* d_out, int out_size, void* d_ws, size_t ws_size,
                              hipStream_t stream) {
    const float* feat   = (const float*)d_in[0];
    const float* W      = (const float*)d_in[1];
    const float* attn_l = (const float*)d_in[2];
    const float* attn_r = (const float*)d_in[3];
    const int*   src    = (const int*)d_in[4];
    const int*   dst    = (const int*)d_in[5];
    const int N = in_sizes[0] / IN_FEATS;
    const int E = in_sizes[4];
    float* out = (float*)d_out;

    char* p = (char*)d_ws;
    auto alloc = [&](size_t bytes) -> char* {
        char* r = p;
        p += (bytes + 255) & ~(size_t)255;
        return r;
    };
    const int nbuckets = (N + 255) / 256;          // 196
    const int nslices = nbuckets * 8;              // 1568
    const int edges_cap = nslices * SCAP;

    __bf16* hb    = (__bf16*)alloc((size_t)N * OUT_FEATS * sizeof(__bf16));
    __bf16* Wb    = (__bf16*)alloc((size_t)OUT_FEATS * IN_FEATS * sizeof(__bf16));
    float* el     = (float*)alloc((size_t)N * sizeof(float));
    float* er     = (float*)alloc((size_t)N * sizeof(float));
    int*   bin_cur = (int*)alloc((size_t)NBINS * sizeof(int));
    int*   row_beg = (int*)alloc((size_t)N * sizeof(int));
    int*   row_end = (int*)alloc((size_t)N * sizeof(int));
    unsigned* arena = (unsigned*)alloc((size_t)NBINS * CAPB * sizeof(unsigned));
    unsigned* edges = (unsigned*)alloc((size_t)edges_cap * sizeof(unsigned));

    prep<<<dim3((OUT_FEATS * IN_FEATS + 255) / 256), dim3(256), 0, stream>>>(
        W, Wb, OUT_FEATS * IN_FEATS, bin_cur);

    gemm_mfma<<<dim3((N + 63) / 64), dim3(256), 0, stream>>>(feat, Wb, attn_l, attn_r,
                                                             hb, el, er, N);

    scatter_kernel<<<dim3(SCAT_BLOCKS), dim3(256), 0, stream>>>(src, dst, bin_cur,
                                                                arena, E);
    build_csr<<<dim3(nslices), dim3(256), 0, stream>>>(arena, bin_cur, el, er, edges,
                                                       row_beg, row_end, N, edges_cap);

    gat_kernel<<<dim3((N + 3) / 4), dim3(256), 0, stream>>>(hb, edges, row_beg,
                                                            row_end, out, N);
}

// Round 9
// 207.736 us; speedup vs baseline: 1.2153x; 1.2153x over previous
//
#include <hip/hip_runtime.h>
#include <hip/hip_bf16.h>

// GATConv on gfx950.
// prep (W->bf16 + bin cursor init) | FUSED gemm+scatter (independent work,
// one dispatch: blocks [0,G) do MFMA GEMM w/ el/er epilogue; blocks [G,G+S)
// bucket edges by dst>>8 via LDS hist + one global reservation atomic per
// (block,bin) -> run-contiguous arena writes) | build_csr: one block per
// bucket, bucket staged in 64KB LDS, 256-bin hist+scan -> per-dst rows;
// placement pass computes w=exp(lrelu(el[u]+er[d])) (no max-sub: |e|<~25
// << 88, alpha identical) and writes packed (bf16(w)<<16|src) densely
// (within-bucket scatter stays in one XCD L2) | gat: one wave per dst,
// 8-deep unrolled coalesced bf16 h-row gathers, denom in-register.

#define IN_FEATS 256
#define OUT_FEATS 128
#define NBINS 256              // coarse buckets (dst>>8); 196 used at N=50000
#define CAPB_LOG 14
#define CAPB (1 << CAPB_LOG)   // per-bucket arena capacity (mean 8192, +90sig)
#define SCAT_BLOCKS 512

typedef __bf16 bf16x8 __attribute__((ext_vector_type(8)));
typedef float f32x4 __attribute__((ext_vector_type(4)));

__global__ void prep(const float* __restrict__ W, __bf16* __restrict__ Wb, int nw,
                     int* __restrict__ cur) {
    int i = blockIdx.x * 256 + threadIdx.x;
    if (i < nw) Wb[i] = (__bf16)W[i];
    if (i < NBINS) cur[i] = i << CAPB_LOG;
}

// ---------- FUSED: gemm blocks [0,G) + scatter blocks [G,G+S) ----------
__global__ __launch_bounds__(256) void gemm_scatter(
    const float* __restrict__ feat, const __bf16* __restrict__ Wb,
    const float* __restrict__ attn_l, const float* __restrict__ attn_r,
    __bf16* __restrict__ hb, float* __restrict__ el, float* __restrict__ er,
    const int* __restrict__ src, const int* __restrict__ dst,
    int* __restrict__ bin_cur, unsigned* __restrict__ arena,
    int n, int E, int G) {
    __shared__ int h[NBINS];
    __shared__ int base[NBINS];

    if (blockIdx.x >= G) {
        // ---------------- scatter path ----------------
        const int blk = blockIdx.x - G;
        const int t = threadIdx.x;
        h[t] = 0;
        __syncthreads();
        const int chunk = (E + SCAT_BLOCKS - 1) / SCAT_BLOCKS;
        const int beg = blk * chunk;
        const int end = min(beg + chunk, E);
        for (int i = beg + t; i < end; i += 256)
            atomicAdd(&h[dst[i] >> 8], 1);             // LDS atomic
        __syncthreads();
        if (h[t] > 0)
            base[t] = atomicAdd(&bin_cur[t], h[t]);    // one global atomic/bin
        h[t] = 0;
        __syncthreads();
        for (int i = beg + t; i < end; i += 256) {
            int d = dst[i];
            int bin = d >> 8;
            int pos = base[bin] + atomicAdd(&h[bin], 1);   // LDS rank
            pos = min(pos, ((bin + 1) << CAPB_LOG) - 1);   // clamp (P~0)
            arena[pos] = ((unsigned)d << 16) | (unsigned)src[i];
        }
        return;
    }

    // ---------------- gemm path ----------------
    const int wid = threadIdx.x >> 6;
    const int lane = threadIdx.x & 63;
    const int s = lane & 15;
    const int q = lane >> 4;
    const int m0 = blockIdx.x * 64 + wid * 16;
    if (m0 >= n) return;

    const int mrow = min(m0 + s, n - 1);
    const float* arow = feat + (size_t)mrow * IN_FEATS + q * 8;

    f32x4 acc[8];
#pragma unroll
    for (int nt = 0; nt < 8; nt++) acc[nt] = (f32x4){0.f, 0.f, 0.f, 0.f};

#pragma unroll
    for (int ks = 0; ks < 8; ks++) {
        const int k0 = ks * 32;
        float4 f0 = *(const float4*)(arow + k0);
        float4 f1 = *(const float4*)(arow + k0 + 4);
        bf16x8 a;
        a[0] = (__bf16)f0.x; a[1] = (__bf16)f0.y; a[2] = (__bf16)f0.z; a[3] = (__bf16)f0.w;
        a[4] = (__bf16)f1.x; a[5] = (__bf16)f1.y; a[6] = (__bf16)f1.z; a[7] = (__bf16)f1.w;
#pragma unroll
        for (int nt = 0; nt < 8; nt++) {
            bf16x8 b = *(const bf16x8*)(Wb + (size_t)(nt * 16 + s) * IN_FEATS + k0 + q * 8);
            acc[nt] = __builtin_amdgcn_mfma_f32_16x16x32_bf16(a, b, acc[nt], 0, 0, 0);
        }
    }

    float al[8], ar[8];
#pragma unroll
    for (int nt = 0; nt < 8; nt++) {
        al[nt] = attn_l[nt * 16 + s];
        ar[nt] = attn_r[nt * 16 + s];
    }

#pragma unroll
    for (int r = 0; r < 4; r++) {
        const int row = m0 + q * 4 + r;
        const bool ok = row < n;
        float pl = 0.f, pr = 0.f;
#pragma unroll
        for (int nt = 0; nt < 8; nt++) {
            float v = acc[nt][r];
            if (ok) hb[(size_t)row * OUT_FEATS + nt * 16 + s] = (__bf16)v;
            pl += v * al[nt];
            pr += v * ar[nt];
        }
#pragma unroll
        for (int m = 1; m < 16; m <<= 1) {
            pl += __shfl_xor(pl, m);
            pr += __shfl_xor(pr, m);
        }
        if (ok && s == 0) {
            el[row] = pl;
            er[row] = pr;
        }
    }
}

// ---- build_csr: one block/bucket, LDS-staged; exact rows + dense write ----
__global__ __launch_bounds__(512) void build_csr(const unsigned* __restrict__ arena,
                                                 const int* __restrict__ bin_cur,
                                                 const float* __restrict__ el,
                                                 const float* __restrict__ er,
                                                 unsigned* __restrict__ edges,
                                                 int* __restrict__ row_beg,
                                                 int* __restrict__ row_end,
                                                 int N, int edges_cap) {
    __shared__ unsigned lds[CAPB];       // 64 KB bucket stage
    __shared__ int cnt[256];
    __shared__ int off[256];
    const int b = blockIdx.x;
    const int t = threadIdx.x;
    const int abeg = b << CAPB_LOG;
    const int cnt_in = min(bin_cur[b] - abeg, CAPB);

    // stage bucket into LDS (coalesced, single global read of arena)
    for (int i = t; i < cnt_in; i += 512) lds[i] = arena[abeg + i];
    if (t < 256) cnt[t] = 0;
    __syncthreads();

    for (int i = t; i < cnt_in; i += 512)
        atomicAdd(&cnt[(lds[i] >> 16) & 255], 1);
    __syncthreads();
    if (t < 256) off[t] = cnt[t];
    __syncthreads();
    for (int o = 1; o < 256; o <<= 1) {            // inclusive scan (all-thread barriers)
        int v = (t < 256 && t >= o) ? off[t - o] : 0;
        __syncthreads();
        if (t < 256) off[t] += v;
        __syncthreads();
    }
    int mycnt = 0, excl = 0;
    if (t < 256) {
        mycnt = cnt[t];
        excl = off[t] - mycnt;
    }
    __syncthreads();
    if (t < 256) {
        off[t] = excl;                             // exclusive offsets
        int v = (b << 8) + t;
        if (v < N) {
            row_beg[v] = abeg + excl;
            row_end[v] = abeg + excl + mycnt;
        }
        cnt[t] = 0;
    }
    __syncthreads();

    for (int i = t; i < cnt_in; i += 512) {
        unsigned e = lds[i];
        int d8 = (e >> 16) & 255;
        int u = (int)(e & 0xFFFFu);
        float x = el[u] + er[(b << 8) + d8];
        x = (x > 0.f) ? x : 0.2f * x;
        float w = __expf(x);
        int r = atomicAdd(&cnt[d8], 1);            // LDS rank
        int pos = abeg + off[d8] + r;              // within-bucket region
        pos = min(pos, edges_cap - 1);             // safety clamp (P~0)
        edges[pos] = (__float_as_uint(w) & 0xFFFF0000u) | (unsigned)u;
    }
}

// ---------------- aggregation: one wave per dst node ----------------
__global__ __launch_bounds__(256) void gat_kernel(const __bf16* __restrict__ hb,
                                                  const unsigned* __restrict__ edges,
                                                  const int* __restrict__ row_beg,
                                                  const int* __restrict__ row_end,
                                                  float* __restrict__ out, int n) {
    const int v = blockIdx.x * 4 + (threadIdx.x >> 6);
    if (v >= n) return;
    const int lane = threadIdx.x & 63;
    const int beg = row_beg[v];
    const int end = row_end[v];
    const unsigned* hbu = (const unsigned*)hb;

    float acc0 = 0.f, acc1 = 0.f, wsum = 0.f;
    for (int c0 = beg; c0 < end; c0 += 64) {
        const int nn = min(64, end - c0);
        int my = (c0 + lane < end) ? (int)edges[c0 + lane] : 0;

        int k = 0;
        for (; k + 8 <= nn; k += 8) {
#pragma unroll
            for (int tt = 0; tt < 8; tt++) {
                unsigned e = (unsigned)__shfl(my, k + tt);
                int u = (int)(e & 0xFFFFu);
                float w = __uint_as_float(e & 0xFFFF0000u);
                wsum += w;
                unsigned pair = hbu[(size_t)u * (OUT_FEATS / 2) + lane];
                acc0 += w * __uint_as_float(pair << 16);
                acc1 += w * __uint_as_float(pair & 0xffff0000u);
            }
        }
        for (; k < nn; k++) {
            unsigned e = (unsigned)__shfl(my, k);
            int u = (int)(e & 0xFFFFu);
            float w = __uint_as_float(e & 0xFFFF0000u);
            wsum += w;
            unsigned pair = hbu[(size_t)u * (OUT_FEATS / 2) + lane];
            acc0 += w * __uint_as_float(pair << 16);
            acc1 += w * __uint_as_float(pair & 0xffff0000u);
        }
    }
    const float dnm = fmaxf(wsum, 1e-9f);
    float2 o = make_float2(acc0 / dnm, acc1 / dnm);
    *(float2*)(out + (size_t)v * OUT_FEATS + lane * 2) = o;
}

extern "C" void kernel_launch(void* const* d_in, const int* in_sizes, int n_in,
                              void* d_out, int out_size, void* d_ws, size_t ws_size,
                              hipStream_t stream) {
    const float* feat   = (const float*)d_in[0];
    const float* W      = (const float*)d_in[1];
    const float* attn_l = (const float*)d_in[2];
    const float* attn_r = (const float*)d_in[3];
    const int*   src    = (const int*)d_in[4];
    const int*   dst    = (const int*)d_in[5];
    const int N = in_sizes[0] / IN_FEATS;
    const int E = in_sizes[4];
    float* out = (float*)d_out;

    char* p = (char*)d_ws;
    auto alloc = [&](size_t bytes) -> char* {
        char* r = p;
        p += (bytes + 255) & ~(size_t)255;
        return r;
    };
    const int nbuckets = (N + 255) / 256;          // 196
    const int edges_cap = nbuckets * CAPB;

    __bf16* hb    = (__bf16*)alloc((size_t)N * OUT_FEATS * sizeof(__bf16));
    __bf16* Wb    = (__bf16*)alloc((size_t)OUT_FEATS * IN_FEATS * sizeof(__bf16));
    float* el     = (float*)alloc((size_t)N * sizeof(float));
    float* er     = (float*)alloc((size_t)N * sizeof(float));
    int*   bin_cur = (int*)alloc((size_t)NBINS * sizeof(int));
    int*   row_beg = (int*)alloc((size_t)N * sizeof(int));
    int*   row_end = (int*)alloc((size_t)N * sizeof(int));
    unsigned* arena = (unsigned*)alloc((size_t)NBINS * CAPB * sizeof(unsigned));
    unsigned* edges = (unsigned*)alloc((size_t)edges_cap * sizeof(unsigned));

    prep<<<dim3((OUT_FEATS * IN_FEATS + 255) / 256), dim3(256), 0, stream>>>(
        W, Wb, OUT_FEATS * IN_FEATS, bin_cur);

    const int G = (N + 63) / 64;                   // 782 gemm blocks
    gemm_scatter<<<dim3(G + SCAT_BLOCKS), dim3(256), 0, stream>>>(
        feat, Wb, attn_l, attn_r, hb, el, er, src, dst, bin_cur, arena, N, E, G);

    build_csr<<<dim3(nbuckets), dim3(512), 0, stream>>>(arena, bin_cur, el, er, edges,
                                                        row_beg, row_end, N, edges_cap);

    gat_kernel<<<dim3((N + 3) / 4), dim3(256), 0, stream>>>(hb, edges, row_beg,
                                                            row_end, out, N);
}